// Round 7
// baseline (280.708 us; speedup 1.0000x reference)
//
#include <hip/hip_runtime.h>
#include <hip/hip_bf16.h>
#include <math.h>

// ---------------------------------------------------------------------------
// QuanvolutionAutoencoder, B=4096, fp32 in/out.
//   feats = quanv(x, theta)                     [4096,784]
//   h1    = relu(feats @ W1 + b1)               [4096,512]
//   h2    = relu(h1 @ (W2@W3) + (b2@W3 + b3))   [4096,512]   (GEMM2+3 fused)
//   out   = sigmoid(h2 @ W4 + b4)               [4096,784]
// SINGLE persistent kernel (512 blocks, guaranteed co-resident at 2/CU by
// LDS=64KB + launch_bounds), phases separated by device-scope grid barriers.
// GEMM per tile: 64x64, BK=128, double-buffered LDS, XOR-swizzled staging
// (round-5-verified body). Plus one 16-byte memset node for barrier counters.
// ---------------------------------------------------------------------------

#define BATCH   4096
#define NPATCH  196
#define FEATDIM 784
#define KP1     896     // K for GEMM1 padded to 7*128
#define NP4     832     // N for GEMM4 padded to 13*64
#define NB      512     // persistent grid size

typedef __bf16 b8 __attribute__((ext_vector_type(8)));
typedef float  f4 __attribute__((ext_vector_type(4)));

__device__ __forceinline__ unsigned short f2bf(float f) {
    unsigned u = __float_as_uint(f);
    u += 0x7FFF + ((u >> 16) & 1);          // round-to-nearest-even
    return (unsigned short)(u >> 16);
}

__device__ __forceinline__ void gload16(const void* g, void* l) {
    __builtin_amdgcn_global_load_lds(
        (const __attribute__((address_space(1))) unsigned int*)g,
        (__attribute__((address_space(3))) unsigned int*)l, 16, 0, 0);
}

// Device-scope grid barrier (all NB blocks co-resident by construction).
__device__ __forceinline__ void grid_barrier(unsigned* cnt, unsigned expected) {
    __syncthreads();
    if (threadIdx.x == 0) {
        __threadfence();    // release: L2 writeback for cross-XCD consumers
        __hip_atomic_fetch_add(cnt, 1u, __ATOMIC_ACQ_REL, __HIP_MEMORY_SCOPE_AGENT);
        while (__hip_atomic_load(cnt, __ATOMIC_ACQUIRE, __HIP_MEMORY_SCOPE_AGENT)
               < expected)
            __builtin_amdgcn_s_sleep(8);
        __threadfence();    // acquire
    }
    __syncthreads();
}

// ---------------------------------------------------------------------------
// Prep unit ranges (same bodies as round 5, KP1=896 layout)
// ---------------------------------------------------------------------------
#define Q_END   3136
#define T1_END  3248
#define T4_END  3352
#define FW_END  4376
#define FB_END  4378
#define ZF_END  4602

// ---------------------------------------------------------------------------
// One 64x64 GEMM tile, BK=128, dbuf LDS (round-5-verified body).
// ACT: 1=relu, 2=sigmoid. OUT_BF16: 1 -> bf16 C, 0 -> fp32 C.
// ---------------------------------------------------------------------------
template <int ACT, int OUT_BF16>
__device__ __forceinline__ void gemm_tile(
    const unsigned short* __restrict__ A,   // [M][lda]
    const unsigned short* __restrict__ BT,  // [Npad][ldb]
    const float* __restrict__ bias, void* __restrict__ C,
    int lda, int ldb, int ldc, int Nlog, int nkt,
    int row0, int col0, unsigned short* As, unsigned short* Bs) {

    const int t  = threadIdx.x;
    const int w  = t >> 6;
    const int l  = t & 63;
    const int wm = w >> 1;
    const int wn = w & 1;

    const int sr = l >> 3;
    const int sc = ((l & 7) ^ sr) * 8;
    const unsigned short* Ab = A  + (size_t)(row0 + w * 8 + sr) * lda + sc;
    const unsigned short* Bb = BT + (size_t)(col0 + w * 8 + sr) * ldb + sc;

    const int q  = l >> 4;
    const int lx = l & 15;
    const int sx = l & 7;
    const int coff[2] = { ((0 + q) ^ sx) * 16, ((4 + q) ^ sx) * 16 };

    f4 acc[2][2];
#pragma unroll
    for (int m = 0; m < 2; ++m)
#pragma unroll
        for (int n = 0; n < 2; ++n) acc[m][n] = (f4)0.f;

    auto stage = [&](int bi, int kt) {
#pragma unroll
        for (int h = 0; h < 2; ++h) {
            const size_t k0 = (size_t)kt * 128 + h * 64;
            char* la = (char*)(As + (bi * 2 + h) * 4096) + w * 1024;
            char* lb = (char*)(Bs + (bi * 2 + h) * 4096) + w * 1024;
            gload16(Ab + k0, la);
            gload16(Bb + k0, lb);
            gload16(Ab + (size_t)32 * lda + k0, la + 4096);
            gload16(Bb + (size_t)32 * ldb + k0, lb + 4096);
        }
    };

    auto compute = [&](int bi) {
#pragma unroll
        for (int h = 0; h < 2; ++h) {
            const char* la = (const char*)(As + (bi * 2 + h) * 4096);
            const char* lb = (const char*)(Bs + (bi * 2 + h) * 4096);
#pragma unroll
            for (int kk = 0; kk < 2; ++kk) {
                const int co = coff[kk];
                b8 a[2], bf[2];
#pragma unroll
                for (int m = 0; m < 2; ++m)
                    a[m] = *(const b8*)(la + (wm * 32 + m * 16 + lx) * 128 + co);
#pragma unroll
                for (int n = 0; n < 2; ++n)
                    bf[n] = *(const b8*)(lb + (wn * 32 + n * 16 + lx) * 128 + co);
#pragma unroll
                for (int m = 0; m < 2; ++m)
#pragma unroll
                    for (int n = 0; n < 2; ++n)
                        acc[m][n] = __builtin_amdgcn_mfma_f32_16x16x32_bf16(
                            a[m], bf[n], acc[m][n], 0, 0, 0);
            }
        }
    };

    stage(0, 0);
    __syncthreads();
    for (int kt = 0; kt < nkt; ++kt) {
        if (kt + 1 < nkt) stage((kt + 1) & 1, kt + 1);
        compute(kt & 1);
        __syncthreads();
    }

#pragma unroll
    for (int n = 0; n < 2; ++n) {
        int col = col0 + wn * 32 + n * 16 + lx;
        if (col >= Nlog) continue;
        float bv = bias[col];
#pragma unroll
        for (int m = 0; m < 2; ++m) {
            int row = row0 + wm * 32 + m * 16 + q * 4;
#pragma unroll
            for (int r = 0; r < 4; ++r) {
                float v = acc[m][n][r] + bv;
                if (ACT == 1) v = fmaxf(v, 0.f);
                if (ACT == 2) v = 1.0f / (1.0f + __expf(-v));
                if (OUT_BF16)
                    ((unsigned short*)C)[(size_t)(row + r) * ldc + col] = f2bf(v);
                else
                    ((float*)C)[(size_t)(row + r) * ldc + col] = v;
            }
        }
    }
}

// ---------------------------------------------------------------------------
__global__ __launch_bounds__(256, 2)
void fused_kernel(const float* __restrict__ x, const float* __restrict__ theta,
                  const float* __restrict__ W1, const float* __restrict__ b1,
                  const float* __restrict__ W2, const float* __restrict__ b2,
                  const float* __restrict__ W3, const float* __restrict__ b3,
                  const float* __restrict__ W4, const float* __restrict__ b4,
                  unsigned short* __restrict__ featsB,
                  unsigned short* __restrict__ W1B,
                  unsigned short* __restrict__ W4B,
                  unsigned short* __restrict__ WcT,
                  float* __restrict__ bc,
                  unsigned short* __restrict__ h1B,
                  unsigned short* __restrict__ h2B,
                  float* __restrict__ out,
                  unsigned* __restrict__ bar) {
    __shared__ __align__(16) char smem[65536];      // 64 KB -> 2 blocks/CU
    unsigned short* As = (unsigned short*)smem;              // [2][2][4096]
    unsigned short* Bs = (unsigned short*)(smem + 32768);    // [2][2][4096]
    float (*Us)[16] = (float (*)[16])smem;                   // prep: 1 KB
    float (*T)[65]  = (float (*)[65])(smem + 1024);          // prep: 16.6 KB

    const int b   = blockIdx.x;
    const int tid = threadIdx.x;

    // ================= P0: prep =================
    if (tid < 16) {     // build U column tid once (wire w -> bit 3-w)
        const int cb[8] = {3, 2, 1, 0, 3, 2, 1, 0};
        const int tb[8] = {2, 1, 0, 3, 1, 0, 3, 2};
        float v[16];
#pragma unroll
        for (int s = 0; s < 16; ++s) v[s] = (s == tid) ? 1.0f : 0.0f;
        for (int k = 0; k < 8; ++k) {
            float th = theta[k] * 0.5f;
            float ct, st;
            __sincosf(th, &st, &ct);
            int cm = 1 << cb[k], tm = 1 << tb[k];
#pragma unroll
            for (int s = 0; s < 16; ++s) {
                if ((s & cm) && !(s & tm)) {
                    float v0 = v[s], v1 = v[s | tm];
                    v[s]      = ct * v0 - st * v1;
                    v[s | tm] = st * v0 + ct * v1;
                }
            }
        }
#pragma unroll
        for (int s = 0; s < 16; ++s) Us[s][tid] = v[s];
    }
    __syncthreads();

    for (int u = b; u < ZF_END; u += NB) {
        __syncthreads();            // protect smem reuse across units
        if (u < Q_END) {
            // ---------------- quanvolution ----------------
            int n = u * 256 + tid;
            int bb = n / NPATCH;
            int p = n % NPATCH;
            int r = p / 14;
            int c = p % 14;

            const float* img = x + (size_t)bb * FEATDIM;
            float a0 = img[(2 * r) * 28 + 2 * c];
            float a1 = img[(2 * r) * 28 + 2 * c + 1];
            float a2 = img[(2 * r + 1) * 28 + 2 * c];
            float a3 = img[(2 * r + 1) * 28 + 2 * c + 1];

            float amp[4][2];
            __sincosf(a0 * 0.5f, &amp[0][1], &amp[0][0]);
            __sincosf(a1 * 0.5f, &amp[1][1], &amp[1][0]);
            __sincosf(a2 * 0.5f, &amp[2][1], &amp[2][0]);
            __sincosf(a3 * 0.5f, &amp[3][1], &amp[3][0]);

            float av[16];
#pragma unroll
            for (int s = 0; s < 16; ++s)
                av[s] = amp[0][(s >> 3) & 1] * amp[1][(s >> 2) & 1] *
                        amp[2][(s >> 1) & 1] * amp[3][s & 1];

            float m0 = 0.f, m1 = 0.f, m2 = 0.f, m3 = 0.f;
#pragma unroll
            for (int s = 0; s < 16; ++s) {
                float vv = 0.f;
#pragma unroll
                for (int t2 = 0; t2 < 16; ++t2) vv += Us[s][t2] * av[t2];
                float pr = vv * vv;
                m0 += ((s >> 3) & 1) ? -pr : pr;
                m1 += ((s >> 2) & 1) ? -pr : pr;
                m2 += ((s >> 1) & 1) ? -pr : pr;
                m3 += (s & 1)        ? -pr : pr;
            }
            ushort4 o;
            o.x = f2bf(m0); o.y = f2bf(m1); o.z = f2bf(m2); o.w = f2bf(m3);
            *(ushort4*)&featsB[(size_t)bb * KP1 + p * 4] = o;
        } else if (u < T1_END) {
            // -- W1 [784][512] -> W1B [512][896] (transpose, pads zeroed) --
            int bb = u - Q_END;               // 14 kt x 8 nt
            int k0 = (bb / 8) * 64, n0 = (bb % 8) * 64;
            int rr = tid >> 6, c = tid & 63;
#pragma unroll
            for (int i = 0; i < 16; ++i) {
                int r = i * 4 + rr;
                if (k0 + r < FEATDIM) T[r][c] = W1[(size_t)(k0 + r) * 512 + n0 + c];
            }
            __syncthreads();
#pragma unroll
            for (int i = 0; i < 16; ++i) {
                int nn = i * 4 + rr;
                unsigned short v = (k0 + c < FEATDIM) ? f2bf(T[c][nn])
                                                      : (unsigned short)0;
                W1B[(size_t)(n0 + nn) * KP1 + k0 + c] = v;
            }
        } else if (u < T4_END) {
            // -- W4 [512][784] -> W4B [832][512] (transpose, pad rows zeroed) --
            int bb = u - T1_END;              // 8 kt x 13 nt
            int k0 = (bb / 13) * 64, n0 = (bb % 13) * 64;
            int rr = tid >> 6, c = tid & 63;
#pragma unroll
            for (int i = 0; i < 16; ++i) {
                int r = i * 4 + rr;
                T[r][c] = (n0 + c < FEATDIM) ? W4[(size_t)(k0 + r) * FEATDIM + n0 + c]
                                             : 0.f;
            }
            __syncthreads();
#pragma unroll
            for (int i = 0; i < 16; ++i) {
                int nn = i * 4 + rr;
                W4B[(size_t)(n0 + nn) * 512 + k0 + c] = f2bf(T[c][nn]);
            }
        } else if (u < FW_END) {
            // -- WcT[n*512+k] = bf16(sum_i W2[k,i]*W3[i,n]) --
            int idx = (u - T4_END) * 256 + tid;
            int n = idx >> 9, k = idx & 511;
            float s = 0.f;
#pragma unroll
            for (int i = 0; i < 32; ++i) s += W2[k * 32 + i] * W3[i * 512 + n];
            WcT[idx] = f2bf(s);
        } else if (u < FB_END) {
            // -- bc --
            int n = (u - FW_END) * 256 + tid;
            if (n < 512) {
                float s = b3[n];
#pragma unroll
                for (int i = 0; i < 32; ++i) s += b2[i] * W3[i * 512 + n];
                bc[n] = s;
            }
        } else {
            // -- zero featsB pad cols 784..895 (14 float4 per row) --
            int idx = (u - FB_END) * 256 + tid;   // 4096*14
            int row = idx / 14, j = idx % 14;
            *(float4*)&featsB[(size_t)row * KP1 + FEATDIM + j * 8] =
                make_float4(0.f, 0.f, 0.f, 0.f);
        }
    }
    grid_barrier(bar + 0, NB);

    // ================= P1: GEMM1 (512 tiles, 1/block) =================
    {
        int tile = (b & 7) * 64 + (b >> 3);
        int bx = tile & 7, by = tile >> 3;
        gemm_tile<1, 1>(featsB, W1B, b1, h1B, KP1, KP1, 512, 512, 7,
                        by * 64, bx * 64, As, Bs);
    }
    grid_barrier(bar + 1, NB);

    // ================= P2: GEMM3' (512 tiles, 1/block) =================
    {
        int tile = (b & 7) * 64 + (b >> 3);
        int bx = tile & 7, by = tile >> 3;
        gemm_tile<1, 1>(h1B, WcT, bc, h2B, 512, 512, 512, 512, 4,
                        by * 64, bx * 64, As, Bs);
    }
    grid_barrier(bar + 2, NB);

    // ================= P3: GEMM4 (832 tiles, 1-2/block) =================
#pragma unroll
    for (int it = 0; it < 2; ++it) {
        int tin = it * 64 + (b >> 3);
        if (tin < 104) {            // 104 tiles per XCD chunk
            int tile = (b & 7) * 104 + tin;
            int bx = tile % 13, by = tile / 13;
            gemm_tile<2, 0>(h2B, W4B, b4, out, 512, 512, FEATDIM, FEATDIM, 4,
                            by * 64, bx * 64, As, Bs);
        }
    }
}

// ---------------------------------------------------------------------------
extern "C" void kernel_launch(void* const* d_in, const int* in_sizes, int n_in,
                              void* d_out, int out_size, void* d_ws, size_t ws_size,
                              hipStream_t stream) {
    const float* x     = (const float*)d_in[0];
    const float* theta = (const float*)d_in[1];
    const float* W1    = (const float*)d_in[2];
    const float* b1    = (const float*)d_in[3];
    const float* W2    = (const float*)d_in[4];
    const float* b2    = (const float*)d_in[5];
    const float* W3    = (const float*)d_in[6];
    const float* b3    = (const float*)d_in[7];
    const float* W4    = (const float*)d_in[8];
    const float* b4    = (const float*)d_in[9];
    float* out = (float*)d_out;

    // workspace layout
    char* ws = (char*)d_ws;
    unsigned short* featsB = (unsigned short*)ws;   ws += (size_t)BATCH * KP1 * 2;
    unsigned short* W1B    = (unsigned short*)ws;   ws += (size_t)512 * KP1 * 2;
    unsigned short* W4B    = (unsigned short*)ws;   ws += (size_t)NP4 * 512 * 2;
    unsigned short* WcT    = (unsigned short*)ws;   ws += (size_t)512 * 512 * 2;
    float*          bc     = (float*)ws;            ws += 2048;
    unsigned short* h1B    = (unsigned short*)ws;   ws += (size_t)BATCH * 512 * 2;
    unsigned short* h2B    = (unsigned short*)ws;   ws += (size_t)BATCH * 512 * 2;
    unsigned*       bar    = (unsigned*)ws;

    hipMemsetAsync((void*)bar, 0, 16, stream);

    fused_kernel<<<NB, 256, 0, stream>>>(
        x, theta, W1, b1, W2, b2, W3, b3, W4, b4,
        featsB, W1B, W4B, WcT, bc, h1B, h2B, out, bar);
}

// Round 8
// 55.033 us; speedup vs baseline: 5.1008x; 5.1008x over previous
//
#include <hip/hip_runtime.h>
#include <hip/hip_bf16.h>
#include <math.h>

// ---------------------------------------------------------------------------
// QuanvolutionAutoencoder, B=4096, fp32 in/out.
//   feats = quanv(x, theta)                     [4096,784]
//   h1    = relu(feats @ W1 + b1)               [4096,512]
//   h2    = relu(h1 @ (W2@W3) + (b2@W3 + b3))   [4096,512]   (GEMM2+3 fused)
//   out   = sigmoid(h2 @ W4 + b4)               [4096,784]
// 4 dispatches: mega-prep, then 3 bf16 MFMA GEMMs (BK=128, dbuf, XCD swizzle).
// == round-5 design (best measured: 55.6us) + float2 quanv loads + nt stores.
// ---------------------------------------------------------------------------

#define BATCH   4096
#define NPATCH  196
#define FEATDIM 784
#define KP1     896     // K for GEMM1 padded to 7*128
#define NP4     832     // N for GEMM4 padded to 13*64

typedef __bf16 b8 __attribute__((ext_vector_type(8)));
typedef float  f4 __attribute__((ext_vector_type(4)));

__device__ __forceinline__ unsigned short f2bf(float f) {
    unsigned u = __float_as_uint(f);
    u += 0x7FFF + ((u >> 16) & 1);          // round-to-nearest-even
    return (unsigned short)(u >> 16);
}

__device__ __forceinline__ void gload16(const void* g, void* l) {
    __builtin_amdgcn_global_load_lds(
        (const __attribute__((address_space(1))) unsigned int*)g,
        (__attribute__((address_space(3))) unsigned int*)l, 16, 0, 0);
}

// ---------------------------------------------------------------------------
// Mega prep kernel block roles:
//   [0, 3136)        quanv -> featsB (bf16, pitch KP1=896)
//   [3136, 3248)     W1 transpose (LDS-tiled): W1B[n*896+k], all pads zeroed
//   [3248, 3352)     W4 transpose (LDS-tiled): W4B[n*512+k], pad rows zeroed
//   [3352, 4376)     WcT[n*512+k] = bf16(sum_i W2[k,i]*W3[i,n])
//   [4376, 4378)     bc[n] = b3[n] + sum_i b2[i]*W3[i,n]
//   [4378, 4602)     zero featsB pad cols (4096 rows x 112)
// ---------------------------------------------------------------------------
#define Q_END   3136
#define T1_END  3248
#define T4_END  3352
#define FW_END  4376
#define FB_END  4378
#define ZF_END  4602

__global__ __launch_bounds__(256)
void prep_kernel(const float* __restrict__ x, const float* __restrict__ theta,
                 const float* __restrict__ W1, const float* __restrict__ W2,
                 const float* __restrict__ W3, const float* __restrict__ W4,
                 const float* __restrict__ b2, const float* __restrict__ b3,
                 unsigned short* __restrict__ featsB,
                 unsigned short* __restrict__ W1B,
                 unsigned short* __restrict__ W4B,
                 unsigned short* __restrict__ WcT,
                 float* __restrict__ bc) {
    __shared__ float shm[64 * 65];          // 16.6 KB; quanv uses first 256
    const int bid = blockIdx.x;
    const int tid = threadIdx.x;

    if (bid < Q_END) {
        // ---------------- quanvolution ----------------
        float (*Us)[16] = (float (*)[16])shm;
        if (tid < 16) {
            const int cb[8] = {3, 2, 1, 0, 3, 2, 1, 0};
            const int tb[8] = {2, 1, 0, 3, 1, 0, 3, 2};
            float v[16];
#pragma unroll
            for (int s = 0; s < 16; ++s) v[s] = (s == tid) ? 1.0f : 0.0f;
            for (int k = 0; k < 8; ++k) {
                float th = theta[k] * 0.5f;
                float ct, st;
                __sincosf(th, &st, &ct);
                int cm = 1 << cb[k], tm = 1 << tb[k];
#pragma unroll
                for (int s = 0; s < 16; ++s) {
                    if ((s & cm) && !(s & tm)) {
                        float v0 = v[s], v1 = v[s | tm];
                        v[s]      = ct * v0 - st * v1;
                        v[s | tm] = st * v0 + ct * v1;
                    }
                }
            }
#pragma unroll
            for (int s = 0; s < 16; ++s) Us[s][tid] = v[s];
        }
        __syncthreads();

        int n = bid * 256 + tid;
        int b = n / NPATCH;
        int p = n % NPATCH;
        int r = p / 14;
        int c = p % 14;

        const float* img = x + (size_t)b * FEATDIM;
        // 2x2 patch as two float2 loads (8B-aligned: col 2c is even)
        float2 p0 = *(const float2*)&img[(2 * r) * 28 + 2 * c];
        float2 p1 = *(const float2*)&img[(2 * r + 1) * 28 + 2 * c];

        float amp[4][2];
        __sincosf(p0.x * 0.5f, &amp[0][1], &amp[0][0]);
        __sincosf(p0.y * 0.5f, &amp[1][1], &amp[1][0]);
        __sincosf(p1.x * 0.5f, &amp[2][1], &amp[2][0]);
        __sincosf(p1.y * 0.5f, &amp[3][1], &amp[3][0]);

        float av[16];
#pragma unroll
        for (int s = 0; s < 16; ++s)
            av[s] = amp[0][(s >> 3) & 1] * amp[1][(s >> 2) & 1] *
                    amp[2][(s >> 1) & 1] * amp[3][s & 1];

        float m0 = 0.f, m1 = 0.f, m2 = 0.f, m3 = 0.f;
#pragma unroll
        for (int s = 0; s < 16; ++s) {
            float vv = 0.f;
#pragma unroll
            for (int t = 0; t < 16; ++t) vv += Us[s][t] * av[t];
            float pr = vv * vv;
            m0 += ((s >> 3) & 1) ? -pr : pr;
            m1 += ((s >> 2) & 1) ? -pr : pr;
            m2 += ((s >> 1) & 1) ? -pr : pr;
            m3 += (s & 1)        ? -pr : pr;
        }
        ushort4 o;
        o.x = f2bf(m0); o.y = f2bf(m1); o.z = f2bf(m2); o.w = f2bf(m3);
        *(ushort4*)&featsB[(size_t)b * KP1 + p * 4] = o;
    } else if (bid < T1_END) {
        // -- W1 [784][512] -> W1B [512][896] (transpose, all pads zeroed) --
        float (*T)[65] = (float (*)[65])shm;
        int bb = bid - Q_END;               // 14 kt x 8 nt
        int k0 = (bb / 8) * 64, n0 = (bb % 8) * 64;
        int rr = tid >> 6, c = tid & 63;
#pragma unroll
        for (int i = 0; i < 16; ++i) {
            int r = i * 4 + rr;
            if (k0 + r < FEATDIM) T[r][c] = W1[(size_t)(k0 + r) * 512 + n0 + c];
        }
        __syncthreads();
#pragma unroll
        for (int i = 0; i < 16; ++i) {
            int nn = i * 4 + rr;            // output row (n), col k
            unsigned short v = (k0 + c < FEATDIM) ? f2bf(T[c][nn]) : (unsigned short)0;
            W1B[(size_t)(n0 + nn) * KP1 + k0 + c] = v;
        }
    } else if (bid < T4_END) {
        // -- W4 [512][784] -> W4B [832][512] (transpose, pad rows zeroed) --
        float (*T)[65] = (float (*)[65])shm;
        int bb = bid - T1_END;              // 8 kt x 13 nt
        int k0 = (bb / 13) * 64, n0 = (bb % 13) * 64;
        int rr = tid >> 6, c = tid & 63;
#pragma unroll
        for (int i = 0; i < 16; ++i) {
            int r = i * 4 + rr;
            T[r][c] = (n0 + c < FEATDIM) ? W4[(size_t)(k0 + r) * FEATDIM + n0 + c] : 0.f;
        }
        __syncthreads();
#pragma unroll
        for (int i = 0; i < 16; ++i) {
            int nn = i * 4 + rr;
            W4B[(size_t)(n0 + nn) * 512 + k0 + c] = f2bf(T[c][nn]);
        }
    } else if (bid < FW_END) {
        // -- WcT[n*512+k] = bf16(sum_i W2[k,i]*W3[i,n]) --
        int idx = (bid - T4_END) * 256 + tid;   // n*512+k
        int n = idx >> 9, k = idx & 511;
        float s = 0.f;
#pragma unroll
        for (int i = 0; i < 32; ++i) s += W2[k * 32 + i] * W3[i * 512 + n];
        WcT[idx] = f2bf(s);
    } else if (bid < FB_END) {
        // -- bc --
        int n = (bid - FW_END) * 256 + tid;
        if (n < 512) {
            float s = b3[n];
#pragma unroll
            for (int i = 0; i < 32; ++i) s += b2[i] * W3[i * 512 + n];
            bc[n] = s;
        }
    } else {
        // -- zero featsB pad cols 784..895 (14 float4 per row) --
        int idx = (bid - FB_END) * 256 + tid;   // 4096*14
        int row = idx / 14, j = idx % 14;
        *(float4*)&featsB[(size_t)row * KP1 + FEATDIM + j * 8] =
            make_float4(0.f, 0.f, 0.f, 0.f);
    }
}

// ---------------------------------------------------------------------------
// bf16 MFMA GEMM, tile 64x64, BK=128 (two verified 64-wide sub-stages),
// 4 waves (2M x 2N, 32x32 per wave), double-buffered LDS (64 KB),
// global_load_lds(16B) with XOR-swizzled global source, XCD-chunked blockIdx.
// ACT: 1=relu, 2=sigmoid. OUT_BF16: 1 -> bf16 C, 0 -> fp32 C (nt stores).
// ---------------------------------------------------------------------------
template <int ACT, int OUT_BF16>
__global__ __launch_bounds__(256)
void gemm_mfma(const unsigned short* __restrict__ A,   // [M][lda] bf16
               const unsigned short* __restrict__ BT,  // [Npad][ldb] bf16
               const float* __restrict__ bias,         // [Nlog] fp32
               void* __restrict__ C,                   // [M][ldc]
               int lda, int ldb, int ldc, int Nlog, int nkt, int gx) {
    __shared__ __align__(16) unsigned short As[2][2][64 * 64];
    __shared__ __align__(16) unsigned short Bs[2][2][64 * 64];

    // XCD-aware bijective swizzle (grid % 8 == 0 always).
    const int nwg = gridDim.x;
    const int d   = blockIdx.x;
    const int tile = (d & 7) * (nwg >> 3) + (d >> 3);
    const int bx = tile % gx;
    const int by = tile / gx;

    const int t  = threadIdx.x;
    const int w  = t >> 6;       // wave 0..3
    const int l  = t & 63;
    const int wm = w >> 1;       // M half
    const int wn = w & 1;        // N half
    const int row0 = by * 64;
    const int col0 = bx * 64;

    // staging: lane covers one 16B chunk of row (w*8+sr); source k pre-swizzled
    const int sr = l >> 3;                  // 0..7
    const int sc = ((l & 7) ^ sr) * 8;      // source k-offset (elements)
    const unsigned short* Ab = A  + (size_t)(row0 + w * 8 + sr) * lda + sc;
    const unsigned short* Bb = BT + (size_t)(col0 + w * 8 + sr) * ldb + sc;

    // ds_read constants
    const int q  = l >> 4;                  // k-quarter 0..3
    const int lx = l & 15;
    const int sx = l & 7;                   // swizzle key (= frag row & 7)
    const int coff[2] = { ((0 + q) ^ sx) * 16, ((4 + q) ^ sx) * 16 };

    f4 acc[2][2];
#pragma unroll
    for (int m = 0; m < 2; ++m)
#pragma unroll
        for (int n = 0; n < 2; ++n) acc[m][n] = (f4)0.f;

    auto stage = [&](int bi, int kt) {
#pragma unroll
        for (int h = 0; h < 2; ++h) {
            const size_t k0 = (size_t)kt * 128 + h * 64;
            char* la = (char*)&As[bi][h][0] + w * 1024;
            char* lb = (char*)&Bs[bi][h][0] + w * 1024;
            gload16(Ab + k0, la);
            gload16(Bb + k0, lb);
            gload16(Ab + (size_t)32 * lda + k0, la + 4096);
            gload16(Bb + (size_t)32 * ldb + k0, lb + 4096);
        }
    };

    auto compute = [&](int bi) {
#pragma unroll
        for (int h = 0; h < 2; ++h) {
            const char* la = (const char*)&As[bi][h][0];
            const char* lb = (const char*)&Bs[bi][h][0];
#pragma unroll
            for (int kk = 0; kk < 2; ++kk) {
                const int co = coff[kk];
                b8 a[2], bf[2];
#pragma unroll
                for (int m = 0; m < 2; ++m)
                    a[m] = *(const b8*)(la + (wm * 32 + m * 16 + lx) * 128 + co);
#pragma unroll
                for (int n = 0; n < 2; ++n)
                    bf[n] = *(const b8*)(lb + (wn * 32 + n * 16 + lx) * 128 + co);
#pragma unroll
                for (int m = 0; m < 2; ++m)
#pragma unroll
                    for (int n = 0; n < 2; ++n)
                        acc[m][n] = __builtin_amdgcn_mfma_f32_16x16x32_bf16(
                            a[m], bf[n], acc[m][n], 0, 0, 0);
            }
        }
    };

    stage(0, 0);
    __syncthreads();
    for (int kt = 0; kt < nkt; ++kt) {
        if (kt + 1 < nkt) stage((kt + 1) & 1, kt + 1);
        compute(kt & 1);
        __syncthreads();
    }

    // epilogue: C row = base + q*4 + reg, col = base + lx
#pragma unroll
    for (int n = 0; n < 2; ++n) {
        int col = col0 + wn * 32 + n * 16 + lx;
        if (col >= Nlog) continue;
        float bv = bias[col];
#pragma unroll
        for (int m = 0; m < 2; ++m) {
            int row = row0 + wm * 32 + m * 16 + q * 4;
#pragma unroll
            for (int r = 0; r < 4; ++r) {
                float v = acc[m][n][r] + bv;
                if (ACT == 1) v = fmaxf(v, 0.f);
                if (ACT == 2) v = 1.0f / (1.0f + __expf(-v));
                if (OUT_BF16)
                    ((unsigned short*)C)[(size_t)(row + r) * ldc + col] = f2bf(v);
                else
                    __builtin_nontemporal_store(
                        v, &((float*)C)[(size_t)(row + r) * ldc + col]);
            }
        }
    }
}

// ---------------------------------------------------------------------------
extern "C" void kernel_launch(void* const* d_in, const int* in_sizes, int n_in,
                              void* d_out, int out_size, void* d_ws, size_t ws_size,
                              hipStream_t stream) {
    const float* x     = (const float*)d_in[0];
    const float* theta = (const float*)d_in[1];
    const float* W1    = (const float*)d_in[2];
    const float* b1    = (const float*)d_in[3];
    const float* W2    = (const float*)d_in[4];
    const float* b2    = (const float*)d_in[5];
    const float* W3    = (const float*)d_in[6];
    const float* b3    = (const float*)d_in[7];
    const float* W4    = (const float*)d_in[8];
    const float* b4    = (const float*)d_in[9];
    float* out = (float*)d_out;

    // workspace layout
    char* ws = (char*)d_ws;
    unsigned short* featsB = (unsigned short*)ws;   ws += (size_t)BATCH * KP1 * 2;
    unsigned short* W1B    = (unsigned short*)ws;   ws += (size_t)512 * KP1 * 2;
    unsigned short* W4B    = (unsigned short*)ws;   ws += (size_t)NP4 * 512 * 2;
    unsigned short* WcT    = (unsigned short*)ws;   ws += (size_t)512 * 512 * 2;
    float*          bc     = (float*)ws;            ws += 2048;
    unsigned short* h1B    = (unsigned short*)ws;   ws += (size_t)BATCH * 512 * 2;
    unsigned short* h2B    = (unsigned short*)ws;

    prep_kernel<<<ZF_END, 256, 0, stream>>>(
        x, theta, W1, W2, W3, W4, b2, b3, featsB, W1B, W4B, WcT, bc);

    // GEMM1: feats[4096,896] @ W1 -> h1 (relu, bf16); grid 8x64 = 512
    gemm_mfma<1, 1><<<512, 256, 0, stream>>>(
        featsB, W1B, b1, h1B, KP1, KP1, 512, 512, KP1 / 128, 8);
    // GEMM3': h1[4096,512] @ Wc -> h2 (relu, bf16); grid 8x64 = 512
    gemm_mfma<1, 1><<<512, 256, 0, stream>>>(
        h1B, WcT, bc, h2B, 512, 512, 512, 512, 4, 8);
    // GEMM4: h2[4096,512] @ W4 -> out (sigmoid, fp32); grid 13x64 = 832
    gemm_mfma<2, 0><<<832, 256, 0, stream>>>(
        h2B, W4B, b4, out, 512, 512, FEATDIM, FEATDIM, 4, 13);
}